// Round 1
// baseline (16.712 us; speedup 1.0000x reference)
//
#include <hip/hip_runtime.h>
#include <math.h>

// Problem constants (from reference): D_STATE=4096, D_CONV=16, T_IN=4081.
#define SDIM 4096
#define TLEN 4081
#define DC   16
#define NT   1024      // one block, 16 waves
#define NW   16
#define XLS  (SDIM + 32)   // padded x in LDS; need indices up to 4095+15=4110

// out[s] = (S+1)*y[s] + G*(sum_s A[s]*y[s]) + pb
//   y[s]  = sum_k x[s-15+k]*wk[k] + bsum
//   wk[k] = sum_c conv_w[c,0,k]*pw[c];  bsum = dot(conv_b,pw);  a = sum exp(A_p*td)
//   G     = (S - a*(1-a^S)/(1-a)) / (1-a)   (closed form of the f32 scan)
__global__ __launch_bounds__(NT) void mamba_fused(
    const float* __restrict__ x, const float* __restrict__ conv_w,
    const float* __restrict__ conv_b, const float* __restrict__ A_p,
    const float* __restrict__ td, const float* __restrict__ pw,
    const float* __restrict__ pb, float* __restrict__ out)
{
    __shared__ float xls[XLS];
    __shared__ float red[18][NW];
    __shared__ float wk_sh[DC];
    __shared__ float scal[4];

    const int tid  = threadIdx.x;
    const int lane = tid & 63;
    const int wv   = tid >> 6;

    // Stage x into LDS, shifted by pad=15, zero-padded at both ends.
    for (int i = tid; i < XLS; i += NT) {
        int j = i - (DC - 1);
        xls[i] = (j >= 0 && j < TLEN) ? x[j] : 0.0f;
    }

    // ---- Phase 1: block-wide reductions wk[0..15], bsum, a ----
    float wk[DC];
#pragma unroll
    for (int k = 0; k < DC; ++k) wk[k] = 0.0f;
    float bs = 0.0f, as = 0.0f;
    for (int c = tid; c < SDIM; c += NT) {          // 4 channels/thread
        float p = pw[c];
        const float4* wrow = (const float4*)(conv_w + (size_t)c * DC);
#pragma unroll
        for (int q = 0; q < 4; ++q) {
            float4 w4 = wrow[q];
            wk[q * 4 + 0] += w4.x * p;
            wk[q * 4 + 1] += w4.y * p;
            wk[q * 4 + 2] += w4.z * p;
            wk[q * 4 + 3] += w4.w * p;
        }
        bs += conv_b[c] * p;
        as += expf(A_p[c] * td[c]);
    }
    // wave64 butterfly reduce of 18 values
#pragma unroll
    for (int off = 32; off >= 1; off >>= 1) {
#pragma unroll
        for (int k = 0; k < DC; ++k) wk[k] += __shfl_xor(wk[k], off);
        bs += __shfl_xor(bs, off);
        as += __shfl_xor(as, off);
    }
    if (lane == 0) {
#pragma unroll
        for (int k = 0; k < DC; ++k) red[k][wv] = wk[k];
        red[16][wv] = bs;
        red[17][wv] = as;
    }
    __syncthreads();
    if (tid < 18) {
        float v = 0.0f;
        for (int w = 0; w < NW; ++w) v += red[tid][w];
        if (tid < DC) wk_sh[tid] = v;
        else          scal[tid - DC] = v;   // scal[0]=bsum, scal[1]=a
    }
    __syncthreads();

    // ---- Phase 2: 16-tap FIR y[s] + day = sum_s A[s]*y[s] ----
    float wkr[DC];
#pragma unroll
    for (int k = 0; k < DC; ++k) wkr[k] = wk_sh[k];
    const float bsum = scal[0];
    const float a    = scal[1];

    float yv[4];
    float day = 0.0f;
#pragma unroll
    for (int i = 0; i < 4; ++i) {
        int s = tid + i * NT;
        float acc = bsum;
#pragma unroll
        for (int k = 0; k < DC; ++k) acc += xls[s + k] * wkr[k];
        yv[i] = acc;
        day += expf(A_p[s] * td[s]) * acc;
    }
#pragma unroll
    for (int off = 32; off >= 1; off >>= 1) day += __shfl_xor(day, off);
    if (lane == 0) red[0][wv] = day;
    __syncthreads();

    // ---- Phase 3: scalar K = G*day + pb, then final write ----
    if (tid == 0) {
        double d = 0.0;
        for (int w = 0; w < NW; ++w) d += (double)red[0][w];
        double ad = (double)a;
        double aS = pow(ad, (double)SDIM);          // underflows to 0, fine
        double G  = ((double)SDIM - ad * (1.0 - aS) / (1.0 - ad)) / (1.0 - ad);
        scal[2] = (float)(G * d + (double)pb[0]);
    }
    __syncthreads();
    const float K = scal[2];
#pragma unroll
    for (int i = 0; i < 4; ++i) {
        out[tid + i * NT] = (float)(SDIM + 1) * yv[i] + K;
    }
}

extern "C" void kernel_launch(void* const* d_in, const int* in_sizes, int n_in,
                              void* d_out, int out_size, void* d_ws, size_t ws_size,
                              hipStream_t stream) {
    const float* x      = (const float*)d_in[0];
    const float* conv_w = (const float*)d_in[1];
    const float* conv_b = (const float*)d_in[2];
    const float* A_p    = (const float*)d_in[3];
    const float* td     = (const float*)d_in[4];
    const float* pw     = (const float*)d_in[5];
    const float* pb     = (const float*)d_in[6];
    mamba_fused<<<1, NT, 0, stream>>>(x, conv_w, conv_b, A_p, td, pw, pb,
                                      (float*)d_out);
}

// Round 2
// 14.982 us; speedup vs baseline: 1.1155x; 1.1155x over previous
//
#include <hip/hip_runtime.h>
#include <math.h>

// Problem constants (from reference): D_STATE=4096, D_CONV=16, T_IN=4081.
#define SDIM 4096
#define TLEN 4081
#define DC   16
#define NT   1024      // one block, 16 waves
#define NW   16
#define XLS  (SDIM + 32)   // padded x in LDS; need indices up to 4095+15=4110

// out[s] = (S+1)*y[s] + G*(sum_s A[s]*y[s]) + pb
//   y[s]  = sum_k x[s-15+k]*wk[k] + bsum
//   wk[k] = sum_c conv_w[c,0,k]*pw[c];  bsum = dot(conv_b,pw);  a = sum exp(A_p*td)
//   G     = (S - a*(1-a^S)/(1-a)) / (1-a)   (closed form of the f32 scan; a<1 so
//           a^S underflows to 0 — guarded branch instead of double pow)
__global__ __launch_bounds__(NT) void mamba_fused(
    const float* __restrict__ x, const float* __restrict__ conv_w,
    const float* __restrict__ conv_b, const float* __restrict__ A_p,
    const float* __restrict__ td, const float* __restrict__ pw,
    const float* __restrict__ pb, float* __restrict__ out)
{
    __shared__ float xls[XLS];
    __shared__ float red[18][NW];
    __shared__ float wk_sh[DC];
    __shared__ float scal[4];

    const int tid  = threadIdx.x;
    const int lane = tid & 63;
    const int wv   = tid >> 6;

    // Stage x into LDS, shifted by pad=15, zero-padded at both ends.
    for (int i = tid; i < XLS; i += NT) {
        int j = i - (DC - 1);
        xls[i] = (j >= 0 && j < TLEN) ? x[j] : 0.0f;
    }

    // ---- Phase 1: block-wide reductions wk[0..15], bsum, a ----
    // Also cache exa[i] = exp(A_p[c]*td[c]) for reuse in phase 2 (same indices).
    float wk[DC];
#pragma unroll
    for (int k = 0; k < DC; ++k) wk[k] = 0.0f;
    float bs = 0.0f, as = 0.0f;
    float exa[4];
#pragma unroll
    for (int i = 0; i < 4; ++i) {
        int c = tid + i * NT;
        float p = pw[c];
        const float4* wrow = (const float4*)(conv_w + (size_t)c * DC);
#pragma unroll
        for (int q = 0; q < 4; ++q) {
            float4 w4 = wrow[q];
            wk[q * 4 + 0] += w4.x * p;
            wk[q * 4 + 1] += w4.y * p;
            wk[q * 4 + 2] += w4.z * p;
            wk[q * 4 + 3] += w4.w * p;
        }
        bs += conv_b[c] * p;
        float e = expf(A_p[c] * td[c]);
        exa[i] = e;
        as += e;
    }
    // wave64 butterfly reduce of 18 values
#pragma unroll
    for (int off = 32; off >= 1; off >>= 1) {
#pragma unroll
        for (int k = 0; k < DC; ++k) wk[k] += __shfl_xor(wk[k], off);
        bs += __shfl_xor(bs, off);
        as += __shfl_xor(as, off);
    }
    if (lane == 0) {
#pragma unroll
        for (int k = 0; k < DC; ++k) red[k][wv] = wk[k];
        red[16][wv] = bs;
        red[17][wv] = as;
    }
    __syncthreads();
    if (tid < 18) {
        float v = 0.0f;
#pragma unroll
        for (int w = 0; w < NW; ++w) v += red[tid][w];
        if (tid < DC) wk_sh[tid] = v;
        else          scal[tid - DC] = v;   // scal[0]=bsum, scal[1]=a
    }
    __syncthreads();

    // ---- Phase 2: 16-tap FIR y[s] + day = sum_s A[s]*y[s] ----
    float wkr[DC];
#pragma unroll
    for (int k = 0; k < DC; ++k) wkr[k] = wk_sh[k];
    const float bsum = scal[0];
    const float a    = scal[1];

    float yv[4];
    float day = 0.0f;
#pragma unroll
    for (int i = 0; i < 4; ++i) {
        int s = tid + i * NT;
        float acc = bsum;
#pragma unroll
        for (int k = 0; k < DC; ++k) acc += xls[s + k] * wkr[k];
        yv[i] = acc;
        day += exa[i] * acc;                 // exp(A_p[s]*td[s]) cached from phase 1
    }
#pragma unroll
    for (int off = 32; off >= 1; off >>= 1) day += __shfl_xor(day, off);
    if (lane == 0) red[0][wv] = day;
    __syncthreads();

    // ---- Phase 3: scalar K = G*day + pb, then final write ----
    if (tid == 0) {
        double d = 0.0;
#pragma unroll
        for (int w = 0; w < NW; ++w) d += (double)red[0][w];
        double ad  = (double)a;
        double omA = 1.0 - ad;
        // a^SDIM: underflows to 0 for a well below 1; only compute if near 1.
        double aS = (ad > 0.9999) ? exp((double)SDIM * log(ad)) : 0.0;
        double G  = ((double)SDIM - ad * (1.0 - aS) / omA) / omA;
        scal[2] = (float)(G * d + (double)pb[0]);
    }
    __syncthreads();
    const float K = scal[2];
#pragma unroll
    for (int i = 0; i < 4; ++i) {
        out[tid + i * NT] = (float)(SDIM + 1) * yv[i] + K;
    }
}

extern "C" void kernel_launch(void* const* d_in, const int* in_sizes, int n_in,
                              void* d_out, int out_size, void* d_ws, size_t ws_size,
                              hipStream_t stream) {
    const float* x      = (const float*)d_in[0];
    const float* conv_w = (const float*)d_in[1];
    const float* conv_b = (const float*)d_in[2];
    const float* A_p    = (const float*)d_in[3];
    const float* td     = (const float*)d_in[4];
    const float* pw     = (const float*)d_in[5];
    const float* pb     = (const float*)d_in[6];
    mamba_fused<<<1, NT, 0, stream>>>(x, conv_w, conv_b, A_p, td, pw, pb,
                                      (float*)d_out);
}

// Round 3
// 12.103 us; speedup vs baseline: 1.3808x; 1.2379x over previous
//
#include <hip/hip_runtime.h>
#include <math.h>

// Problem constants (from reference): D_STATE=4096, D_CONV=16, T_IN=4081.
#define SDIM 4096
#define TLEN 4081
#define DC   16

#define NB1  64     // kernel1: 64 blocks x 64 threads = 4096 threads, 1 channel each
#define NT1  64
#define NB2  16     // kernel2: 16 blocks x 256 threads = 4096 outputs
#define NT2  256
#define NVAL 34     // partials per block: wk[16], h[16], bsum, a

// Math (exact linear collapse of the reference):
//   y[s]  = sum_k xg[s+k]*wk[k] + bsum,  xg = x zero-padded by DC-1 on the left
//   wk[k] = sum_c conv_w[c,0,k]*pw[c];  bsum = dot(conv_b,pw);  a = sum exp(A_p*td)
//   h[k]  = sum_s exp(A_p[s]*td[s]) * xg[s+k]        (lets day avoid needing wk)
//   day   = sum_s exa[s]*y[s] = sum_k wk[k]*h[k] + bsum*a
//   G     = (S - a*(1-a^S)/(1-a)) / (1-a)            (closed form of the scan)
//   out[s]= (S+1)*y[s] + G*day + pb

// ws layout: ws[j*NB1 + b] = block b's partial of value j (j: 0..15 wk, 16..31 h,
// 32 bsum, 33 a).

__global__ __launch_bounds__(NT1) void k1_partials(
    const float* __restrict__ x, const float* __restrict__ conv_w,
    const float* __restrict__ conv_b, const float* __restrict__ A_p,
    const float* __restrict__ td, const float* __restrict__ pw,
    float* __restrict__ ws)
{
    __shared__ float xt[NT1 + DC];            // xg window for this block's 64 s's
    const int t = threadIdx.x;
    const int b = blockIdx.x;
    const int s = b * NT1 + t;

    // Stage xg[b*64 .. b*64+79]
    for (int i = t; i < NT1 + DC; i += NT1) {
        int j = b * NT1 + i - (DC - 1);
        xt[i] = (j >= 0 && j < TLEN) ? x[j] : 0.0f;
    }

    const float p = pw[s];
    const float4* wrow = (const float4*)(conv_w + (size_t)s * DC);
    float4 w0 = wrow[0], w1 = wrow[1], w2 = wrow[2], w3 = wrow[3];
    float wk[DC] = { w0.x*p, w0.y*p, w0.z*p, w0.w*p,
                     w1.x*p, w1.y*p, w1.z*p, w1.w*p,
                     w2.x*p, w2.y*p, w2.z*p, w2.w*p,
                     w3.x*p, w3.y*p, w3.z*p, w3.w*p };
    float bs = conv_b[s] * p;
    float ea = expf(A_p[s] * td[s]);

    __syncthreads();
    float h[DC];
#pragma unroll
    for (int k = 0; k < DC; ++k) h[k] = ea * xt[t + k];

    // single-wave butterfly reduce of 34 values
#pragma unroll
    for (int off = 32; off >= 1; off >>= 1) {
#pragma unroll
        for (int k = 0; k < DC; ++k) { wk[k] += __shfl_xor(wk[k], off);
                                       h[k]  += __shfl_xor(h[k],  off); }
        bs += __shfl_xor(bs, off);
        ea += __shfl_xor(ea, off);
    }
    if (t == 0) {
#pragma unroll
        for (int k = 0; k < DC; ++k) { ws[k * NB1 + b]        = wk[k];
                                       ws[(DC + k) * NB1 + b] = h[k]; }
        ws[32 * NB1 + b] = bs;
        ws[33 * NB1 + b] = ea;
    }
}

__global__ __launch_bounds__(NT2) void k2_final(
    const float* __restrict__ x, const float* __restrict__ pb,
    const float* __restrict__ ws, float* __restrict__ out)
{
    __shared__ float red[NVAL];
    __shared__ float xt[NT2 + DC];            // xg window for this block's 256 s's
    __shared__ float Ksh;
    const int t = threadIdx.x;
    const int b = blockIdx.x;

    // Final reduction of the 64 block-partials (L2-hot, ~9 KB total).
    if (t < NVAL) {
        const float* col = ws + t * NB1;
        float v = 0.0f;
#pragma unroll
        for (int i = 0; i < NB1; ++i) v += col[i];
        red[t] = v;
    }
    // Stage xg[b*256 .. b*256+270]
    for (int i = t; i < NT2 + DC - 1; i += NT2) {
        int j = b * NT2 + i - (DC - 1);
        xt[i] = (j >= 0 && j < TLEN) ? x[j] : 0.0f;
    }
    __syncthreads();

    if (t == 0) {
        float day = red[32] * red[33];        // bsum * a
#pragma unroll
        for (int k = 0; k < DC; ++k) day += red[k] * red[DC + k];
        double ad  = (double)red[33];
        double omA = 1.0 - ad;
        double aS  = (ad > 0.9999) ? exp((double)SDIM * log(ad)) : 0.0;
        double G   = ((double)SDIM - ad * (1.0 - aS) / omA) / omA;
        Ksh = (float)(G * (double)day + (double)pb[0]);
    }
    __syncthreads();

    float wkr[DC];
#pragma unroll
    for (int k = 0; k < DC; ++k) wkr[k] = red[k];
    const float bsum = red[32];
    const float K    = Ksh;

    float acc = bsum;
#pragma unroll
    for (int k = 0; k < DC; ++k) acc += xt[t + k] * wkr[k];
    out[b * NT2 + t] = (float)(SDIM + 1) * acc + K;
}

extern "C" void kernel_launch(void* const* d_in, const int* in_sizes, int n_in,
                              void* d_out, int out_size, void* d_ws, size_t ws_size,
                              hipStream_t stream) {
    const float* x      = (const float*)d_in[0];
    const float* conv_w = (const float*)d_in[1];
    const float* conv_b = (const float*)d_in[2];
    const float* A_p    = (const float*)d_in[3];
    const float* td     = (const float*)d_in[4];
    const float* pw     = (const float*)d_in[5];
    const float* pb     = (const float*)d_in[6];
    float* ws = (float*)d_ws;

    k1_partials<<<NB1, NT1, 0, stream>>>(x, conv_w, conv_b, A_p, td, pw, ws);
    k2_final<<<NB2, NT2, 0, stream>>>(x, pb, ws, (float*)d_out);
}